// Round 1
// baseline (13978.587 us; speedup 1.0000x reference)
//
#include <hip/hip_runtime.h>
#include <cstddef>

namespace {

constexpr int B = 2048, T = 128, F = 128, H = 512, L = 8, KW = 10;
constexpr int GATES = 2064, GP = 2112, KIN = 640; // GP = 2112 = 33*64 (padded N)
constexpr int HS = 85;                            // H // 6

__device__ __forceinline__ float sigmoidf_(float x) { return 1.0f / (1.0f + expf(-x)); }

// Build merged weight Wc[640][GP] = [Wk[0:128]; Wr[0:512]], zero-padded cols,
// plus wrow = Wk[128]+Wr[512] (dt rank-1 row) and biasc = bk+br.
__global__ void prep_weights(const float* __restrict__ Wk, const float* __restrict__ bk,
                             const float* __restrict__ Wr, const float* __restrict__ br,
                             float* __restrict__ Wc, float* __restrict__ wrow,
                             float* __restrict__ biasc) {
    int idx = blockIdx.x * blockDim.x + threadIdx.x;
    int row = idx / GP, n = idx % GP;
    if (row < KIN) {
        float v = 0.f;
        if (n < GATES) v = (row < F) ? Wk[(size_t)row * GATES + n] : Wr[(size_t)(row - F) * GATES + n];
        Wc[(size_t)row * GP + n] = v;
    } else if (row == KIN) {
        wrow[n] = (n < GATES) ? (Wk[(size_t)F * GATES + n] + Wr[(size_t)H * GATES + n]) : 0.f;
    } else if (row == KIN + 1) {
        biasc[n] = (n < GATES) ? (bk[n] + br[n]) : 0.f;
    }
}

// CWt[h*KW+k][o] = conv_w[o][h][k]  (for the conv einsum as a GEMM)
__global__ void prep_cwt(const float* __restrict__ conv_w, float* __restrict__ CWt) {
    int idx = blockIdx.x * blockDim.x + threadIdx.x;
    if (idx >= H * H * KW) return;
    int o = idx / (H * KW);
    int r = idx % (H * KW);
    CWt[(size_t)r * H + o] = conv_w[idx];
}

// xo[b][n] = sum_k A[b][k]*Wc[k][n] + biasc[n] + dt[b]*wrow[n]
// A[b][k] = k<128 ? x[b][t][k] : h[b][k-128]
__global__ __launch_bounds__(256) void step_gemm(
    const float* __restrict__ x, const float* __restrict__ hbuf,
    const float* __restrict__ Wc, const float* __restrict__ wrow,
    const float* __restrict__ biasc, const float* __restrict__ tme,
    float* __restrict__ xo, int t)
{
    __shared__ float As[16][68];
    __shared__ float Bs[16][64];
    const int tid = threadIdx.x;
    const int n0 = blockIdx.x * 64, m0 = blockIdx.y * 64;

    const int am = tid >> 2, ak = (tid & 3) << 2;     // A loader: row am, 4 k's at ak
    const int bkr = tid >> 4, bn = (tid & 15) << 2;   // B loader: k-row bkr, 4 n's at bn
    const int tn = (tid & 15) << 2, tm = (tid >> 4) << 2;

    float acc[4][4] = {};

    for (int k0 = 0; k0 < KIN; k0 += 16) {
        int gk = k0 + ak;   // whole 16-tile is on one side of the x/h split (128%16==0)
        const float* ap = (gk < F)
            ? (x + (size_t)(m0 + am) * (T * F) + (size_t)t * F + gk)
            : (hbuf + (size_t)(m0 + am) * H + (gk - F));
        float4 av = *(const float4*)ap;
        As[ak + 0][am] = av.x;
        As[ak + 1][am] = av.y;
        As[ak + 2][am] = av.z;
        As[ak + 3][am] = av.w;
        *(float4*)&Bs[bkr][bn] = *(const float4*)(Wc + (size_t)(k0 + bkr) * GP + n0 + bn);
        __syncthreads();
#pragma unroll
        for (int k = 0; k < 16; ++k) {
            float4 a4 = *(const float4*)&As[k][tm];
            float4 b4 = *(const float4*)&Bs[k][tn];
            acc[0][0] += a4.x * b4.x; acc[0][1] += a4.x * b4.y; acc[0][2] += a4.x * b4.z; acc[0][3] += a4.x * b4.w;
            acc[1][0] += a4.y * b4.x; acc[1][1] += a4.y * b4.y; acc[1][2] += a4.y * b4.z; acc[1][3] += a4.y * b4.w;
            acc[2][0] += a4.z * b4.x; acc[2][1] += a4.z * b4.y; acc[2][2] += a4.z * b4.z; acc[2][3] += a4.z * b4.w;
            acc[3][0] += a4.w * b4.x; acc[3][1] += a4.w * b4.y; acc[3][2] += a4.w * b4.z; acc[3][3] += a4.w * b4.w;
        }
        __syncthreads();
    }

    float4 bias4 = *(const float4*)(biasc + n0 + tn);
    float4 wr4 = *(const float4*)(wrow + n0 + tn);
#pragma unroll
    for (int r = 0; r < 4; ++r) {
        int m = m0 + tm + r;
        float dtv = tme[(size_t)m * T + t];
        float4 o4;
        o4.x = acc[r][0] + bias4.x + dtv * wr4.x;
        o4.y = acc[r][1] + bias4.y + dtv * wr4.y;
        o4.z = acc[r][2] + bias4.z + dtv * wr4.z;
        o4.w = acc[r][3] + bias4.w + dtv * wr4.w;
        *(float4*)(xo + (size_t)m * GP + n0 + tn) = o4;
    }
}

// Gates, cell/hidden update, distance, rolling K-window. One block (64 thr) per batch row.
__global__ __launch_bounds__(64) void step_point(
    const float* __restrict__ xo, float* __restrict__ c, float* __restrict__ hbuf,
    float* __restrict__ tmp_h, float* __restrict__ tmp_dis, float* __restrict__ dist_out,
    int t)
{
    const int b = blockIdx.x;
    const int tid = threadIdx.x;
    const float* row = xo + (size_t)b * GP;

    float fz[L], iz[L];
#pragma unroll
    for (int j = 0; j < L; ++j) { fz[j] = row[j]; iz[j] = row[L + j]; }

    float mx = fz[0];
#pragma unroll
    for (int j = 1; j < L; ++j) mx = fmaxf(mx, fz[j]);
    float s = 0.f;
#pragma unroll
    for (int j = 0; j < L; ++j) { fz[j] = expf(fz[j] - mx); s += fz[j]; }
    float fm[L];
    float run = 0.f;
#pragma unroll
    for (int j = 0; j < L; ++j) { run += fz[j]; fm[j] = run / s; }

    mx = iz[0];
#pragma unroll
    for (int j = 1; j < L; ++j) mx = fmaxf(mx, iz[j]);
    s = 0.f;
#pragma unroll
    for (int j = 0; j < L; ++j) { iz[j] = expf(iz[j] - mx); s += iz[j]; }
    float im[L];
    run = 0.f;
#pragma unroll
    for (int j = L - 1; j >= 0; --j) { run += iz[j]; im[j] = run / s; }

#pragma unroll
    for (int l = 0; l < L; ++l) {
        int hidx = l * 64 + tid;  // lane-contiguous within chunk -> coalesced
        float ov = fm[l] * im[l];
        float fg = sigmoidf_(row[16 + l * 64 + tid]);
        float ig = sigmoidf_(row[16 + 512 + l * 64 + tid]);
        float og = sigmoidf_(row[16 + 1024 + l * 64 + tid]);
        float cg = tanhf(row[16 + 1536 + l * 64 + tid]);
        float cl = c[(size_t)b * H + hidx];
        float cn = ov * (fg * cl + ig * cg) + (fm[l] - ov) * cl + (im[l] - ov) * cg;
        float hn = og * tanhf(cn);
        c[(size_t)b * H + hidx] = cn;
        hbuf[(size_t)b * H + hidx] = hn;
        if (t >= T - KW) tmp_h[((size_t)(t - (T - KW)) * B + b) * H + hidx] = hn;
    }
    if (tid == 0) {
        float a = 0.f;
#pragma unroll
        for (int j = 0; j < L; ++j) a += fm[j];
        float d = 1.0f - a / (float)L;
        dist_out[(size_t)t * B + b] = d;
        if (t >= T - KW) tmp_dis[(size_t)(t - (T - KW)) * B + b] = d;
    }
}

// local_dis softmax(cumsum), mean_h, and Ahk[b][h*KW+k] = tmp_h[k][b][h]*local_dis[b][k]
__global__ __launch_bounds__(128) void post_local(
    const float* __restrict__ tmp_h, const float* __restrict__ tmp_dis,
    float* __restrict__ mean_h, float* __restrict__ Ahk)
{
    const int b = blockIdx.x;
    const int tid = threadIdx.x;
    __shared__ float ld[KW];
    if (tid == 0) {
        float cd[KW];
        float run = 0.f;
        for (int k = 0; k < KW; ++k) { run += tmp_dis[(size_t)k * B + b]; cd[k] = run; }
        float mx = cd[0];
        for (int k = 1; k < KW; ++k) mx = fmaxf(mx, cd[k]);
        float s = 0.f;
        for (int k = 0; k < KW; ++k) { cd[k] = expf(cd[k] - mx); s += cd[k]; }
        for (int k = 0; k < KW; ++k) ld[k] = cd[k] / s;
    }
    __syncthreads();
    float ldr[KW];
#pragma unroll
    for (int k = 0; k < KW; ++k) ldr[k] = ld[k];
    for (int h = tid; h < H; h += 128) {
        float s = 0.f;
#pragma unroll
        for (int k = 0; k < KW; ++k) {
            float v = tmp_h[((size_t)k * B + b) * H + h] * ldr[k];
            s += v;
            Ahk[(size_t)b * (H * KW) + (size_t)h * KW + k] = v;
        }
        mean_h[(size_t)b * H + h] = s * (1.0f / KW);
    }
}

__global__ void theme1_k(const float* __restrict__ mean_h, const float* __restrict__ Ws,
                         const float* __restrict__ bs, float* __restrict__ t1)
{
    int idx = blockIdx.x * blockDim.x + threadIdx.x;
    if (idx >= B * HS) return;
    int b = idx / HS, j = idx % HS;
    float s = bs[j];
    const float* mh = mean_h + (size_t)b * H;
    for (int h = 0; h < H; ++h) s += mh[h] * Ws[(size_t)h * HS + j];
    t1[idx] = fmaxf(s, 0.f);
}

__global__ void theme2_k(const float* __restrict__ t1, const float* __restrict__ Wrs,
                         const float* __restrict__ brs, float* __restrict__ theme)
{
    int idx = blockIdx.x * blockDim.x + threadIdx.x;
    if (idx >= B * H) return;
    int b = idx / H, o = idx % H;
    float s = brs[o];
    const float* tv = t1 + (size_t)b * HS;
    for (int j = 0; j < HS; ++j) s += tv[j] * Wrs[(size_t)j * H + o];
    theme[idx] = sigmoidf_(s);
}

// out0[b][o] = theme[b][o] * (sum_k Ahk[b][k]*CWt[k][o] + conv_b[o]);  K = 5120
__global__ __launch_bounds__(256) void conv_gemm(
    const float* __restrict__ Ahk, const float* __restrict__ CWt,
    const float* __restrict__ conv_b, const float* __restrict__ theme,
    float* __restrict__ out0)
{
    __shared__ float As[16][68];
    __shared__ float Bs[16][64];
    const int tid = threadIdx.x;
    const int n0 = blockIdx.x * 64, m0 = blockIdx.y * 64;
    const int am = tid >> 2, ak = (tid & 3) << 2;
    const int bkr = tid >> 4, bn = (tid & 15) << 2;
    const int tn = (tid & 15) << 2, tm = (tid >> 4) << 2;
    float acc[4][4] = {};
    for (int k0 = 0; k0 < H * KW; k0 += 16) {
        float4 av = *(const float4*)(Ahk + (size_t)(m0 + am) * (H * KW) + k0 + ak);
        As[ak + 0][am] = av.x; As[ak + 1][am] = av.y; As[ak + 2][am] = av.z; As[ak + 3][am] = av.w;
        *(float4*)&Bs[bkr][bn] = *(const float4*)(CWt + (size_t)(k0 + bkr) * H + n0 + bn);
        __syncthreads();
#pragma unroll
        for (int k = 0; k < 16; ++k) {
            float4 a4 = *(const float4*)&As[k][tm];
            float4 b4 = *(const float4*)&Bs[k][tn];
            acc[0][0] += a4.x * b4.x; acc[0][1] += a4.x * b4.y; acc[0][2] += a4.x * b4.z; acc[0][3] += a4.x * b4.w;
            acc[1][0] += a4.y * b4.x; acc[1][1] += a4.y * b4.y; acc[1][2] += a4.y * b4.z; acc[1][3] += a4.y * b4.w;
            acc[2][0] += a4.z * b4.x; acc[2][1] += a4.z * b4.y; acc[2][2] += a4.z * b4.z; acc[2][3] += a4.z * b4.w;
            acc[3][0] += a4.w * b4.x; acc[3][1] += a4.w * b4.y; acc[3][2] += a4.w * b4.z; acc[3][3] += a4.w * b4.w;
        }
        __syncthreads();
    }
    float4 cb4 = *(const float4*)(conv_b + n0 + tn);
#pragma unroll
    for (int r = 0; r < 4; ++r) {
        int m = m0 + tm + r;
        float4 th4 = *(const float4*)(theme + (size_t)m * H + n0 + tn);
        float4 o4;
        o4.x = th4.x * (acc[r][0] + cb4.x);
        o4.y = th4.y * (acc[r][1] + cb4.y);
        o4.z = th4.z * (acc[r][2] + cb4.z);
        o4.w = th4.w * (acc[r][3] + cb4.w);
        *(float4*)(out0 + (size_t)m * H + n0 + tn) = o4;
    }
}

} // namespace

extern "C" void kernel_launch(void* const* d_in, const int* in_sizes, int n_in,
                              void* d_out, int out_size, void* d_ws, size_t ws_size,
                              hipStream_t stream)
{
    (void)in_sizes; (void)n_in; (void)out_size; (void)ws_size;
    const float* x      = (const float*)d_in[0];
    const float* tme    = (const float*)d_in[1];
    const float* Wk     = (const float*)d_in[2];
    const float* bk     = (const float*)d_in[3];
    const float* Wr     = (const float*)d_in[4];
    const float* br     = (const float*)d_in[5];
    const float* Ws     = (const float*)d_in[6];
    const float* bs     = (const float*)d_in[7];
    const float* Wrs    = (const float*)d_in[8];
    const float* brs    = (const float*)d_in[9];
    const float* conv_w = (const float*)d_in[10];
    const float* conv_b = (const float*)d_in[11];

    float* out0 = (float*)d_out;
    float* dist_out = out0 + (size_t)B * H;   // distance (T, B)

    // workspace layout (floats); total ~33.7M floats (~135 MB)
    float* w = (float*)d_ws;
    float* Wc     = w; w += (size_t)KIN * GP;
    float* wrow   = w; w += GP;
    float* biasc  = w; w += GP;
    float* xo     = w; w += (size_t)B * GP;
    float* c      = w; w += (size_t)B * H;
    float* hbuf   = w; w += (size_t)B * H;
    float* tmp_h  = w; w += (size_t)KW * B * H;
    float* tmp_ds = w; w += (size_t)KW * B;
    float* mean_h = w; w += (size_t)B * H;
    float* t1     = w; w += (size_t)B * HS;
    float* theme  = w; w += (size_t)B * H;
    float* Ahk    = w; w += (size_t)B * H * KW;
    float* CWt    = w; w += (size_t)H * KW * H;

    hipMemsetAsync(c, 0, (size_t)B * H * sizeof(float), stream);
    hipMemsetAsync(hbuf, 0, (size_t)B * H * sizeof(float), stream);

    prep_weights<<<((KIN + 2) * GP + 255) / 256, 256, 0, stream>>>(Wk, bk, Wr, br, Wc, wrow, biasc);
    prep_cwt<<<(H * H * KW + 255) / 256, 256, 0, stream>>>(conv_w, CWt);

    for (int t = 0; t < T; ++t) {
        step_gemm<<<dim3(GP / 64, B / 64), 256, 0, stream>>>(x, hbuf, Wc, wrow, biasc, tme, xo, t);
        step_point<<<B, 64, 0, stream>>>(xo, c, hbuf, tmp_h, tmp_ds, dist_out, t);
    }

    post_local<<<B, 128, 0, stream>>>(tmp_h, tmp_ds, mean_h, Ahk);
    theme1_k<<<(B * HS + 255) / 256, 256, 0, stream>>>(mean_h, Ws, bs, t1);
    theme2_k<<<(B * H + 255) / 256, 256, 0, stream>>>(t1, Wrs, brs, theme);
    conv_gemm<<<dim3(H / 64, B / 64), 256, 0, stream>>>(Ahk, CWt, conv_b, theme, out0);
}

// Round 2
// 4687.680 us; speedup vs baseline: 2.9820x; 2.9820x over previous
//
#include <hip/hip_runtime.h>
#include <hip/hip_bf16.h>
#include <cstddef>
#include <cstdint>

namespace {

constexpr int B = 2048, T = 128, F = 128, H = 512, L = 8, KW = 10;
constexpr int GATES = 2064;
constexpr int GPo = 2176;   // padded N: 17 * 128
constexpr int KIN = 640;    // F + H
constexpr int HS = 85;      // H // 6

typedef __attribute__((ext_vector_type(8))) short short8;
typedef __attribute__((ext_vector_type(4))) float f32x4;

__device__ __forceinline__ float sigmoidf_(float x) { return 1.0f / (1.0f + expf(-x)); }

__device__ __forceinline__ void gl_lds16(const void* g, void* l) {
    __builtin_amdgcn_global_load_lds(
        (const __attribute__((address_space(1))) unsigned int*)g,
        (__attribute__((address_space(3))) unsigned int*)l,
        16, 0, 0);
}

// ---------- prep ----------
// WcT[n][k] bf16, n-major (k contiguous): n<GATES: k<F ? Wk[k][n] : Wr[k-F][n]; else 0
// wrow[n] = Wk[F][n] + Wr[H][n] (dt rank-1 row), biasc[n] = bk[n]+br[n]  (fp32, padded)
__global__ void prep_weights(const float* __restrict__ Wk, const float* __restrict__ bk,
                             const float* __restrict__ Wr, const float* __restrict__ br,
                             __hip_bfloat16* __restrict__ WcT, float* __restrict__ wrow,
                             float* __restrict__ biasc) {
    int idx = blockIdx.x * blockDim.x + threadIdx.x;
    const int NW = GPo * KIN;
    if (idx < NW) {
        int n = idx / KIN, k = idx % KIN;
        float v = 0.f;
        if (n < GATES) v = (k < F) ? Wk[(size_t)k * GATES + n] : Wr[(size_t)(k - F) * GATES + n];
        WcT[idx] = __float2bfloat16(v);
    } else if (idx < NW + GPo) {
        int n = idx - NW;
        wrow[n] = (n < GATES) ? (Wk[(size_t)F * GATES + n] + Wr[(size_t)H * GATES + n]) : 0.f;
    } else if (idx < NW + 2 * GPo) {
        int n = idx - NW - GPo;
        biasc[n] = (n < GATES) ? (bk[n] + br[n]) : 0.f;
    }
}

__global__ void convert_x(const float* __restrict__ x, __hip_bfloat16* __restrict__ xb) {
    int i = blockIdx.x * blockDim.x + threadIdx.x;  // 4 elems per thread
    size_t o = (size_t)i * 4;
    if (o >= (size_t)B * T * F) return;
    float4 v = *(const float4*)(x + o);
    xb[o + 0] = __float2bfloat16(v.x);
    xb[o + 1] = __float2bfloat16(v.y);
    xb[o + 2] = __float2bfloat16(v.z);
    xb[o + 3] = __float2bfloat16(v.w);
}

// CWt[h*KW+k][o] = conv_w[o][h][k]
__global__ void prep_cwt(const float* __restrict__ conv_w, float* __restrict__ CWt) {
    int idx = blockIdx.x * blockDim.x + threadIdx.x;
    if (idx >= H * H * KW) return;
    int o = idx / (H * KW);
    int r = idx % (H * KW);
    CWt[(size_t)r * H + o] = conv_w[idx];
}

// ---------- per-step GEMM (bf16 MFMA, m97 structure) ----------
// xo[b][n] = sum_k A[b][k]*WcT[n][k] + biasc[n] + dt[b]*wrow[n]
// A[b][k] = k<128 ? xb[b][t][k] : hb[b][k-128]
__global__ __launch_bounds__(256) void step_gemm_mfma(
    const __hip_bfloat16* __restrict__ xb, const __hip_bfloat16* __restrict__ hb,
    const __hip_bfloat16* __restrict__ WcT, const float* __restrict__ wrow,
    const float* __restrict__ biasc, const float* __restrict__ tme,
    float* __restrict__ xo, int t)
{
    // [row][32 k] bf16, 64B per row, 8 KB each
    __shared__ __align__(16) unsigned short As[128 * 32];
    __shared__ __align__(16) unsigned short Bs[128 * 32];

    const int tid = threadIdx.x;
    const int wave = tid >> 6, lane = tid & 63;
    const int m0 = blockIdx.y * 128, n0 = blockIdx.x * 128;
    const int wr = wave >> 1, wc = wave & 1;  // wave tile origin (wr*64, wc*64)
    const int quad = lane >> 4, m16 = lane & 15;

    f32x4 acc[4][4] = {};

    for (int k0 = 0; k0 < KIN; k0 += 32) {
        const bool from_x = (k0 < F);  // whole 32-tile on one side (128 % 32 == 0)
#pragma unroll
        for (int r = 0; r < 2; ++r) {
            const int o = r * 4096 + wave * 1024 + lane * 16;  // byte offset in tile
            const int row = o >> 6;
            const int kg = k0 + ((o >> 4) & 3) * 8;
            const __hip_bfloat16* asrc = from_x
                ? (xb + ((size_t)(m0 + row) * T + t) * F + kg)
                : (hb + (size_t)(m0 + row) * H + (kg - F));
            gl_lds16(asrc, (char*)As + o);
            const __hip_bfloat16* bsrc = WcT + (size_t)(n0 + row) * KIN + kg;
            gl_lds16(bsrc, (char*)Bs + o);
        }
        __syncthreads();

        short8 av[4], bv[4];
#pragma unroll
        for (int i = 0; i < 4; ++i)
            av[i] = *(const short8*)((const char*)As + ((wr * 64 + i * 16 + m16) * 64 + quad * 16));
#pragma unroll
        for (int j = 0; j < 4; ++j)
            bv[j] = *(const short8*)((const char*)Bs + ((wc * 64 + j * 16 + m16) * 64 + quad * 16));
#pragma unroll
        for (int i = 0; i < 4; ++i)
#pragma unroll
            for (int j = 0; j < 4; ++j)
                acc[i][j] = __builtin_amdgcn_mfma_f32_16x16x32_bf16(av[i], bv[j], acc[i][j], 0, 0, 0);
        __syncthreads();
    }

    // epilogue: C layout col = lane&15, row = quad*4 + r
#pragma unroll
    for (int j = 0; j < 4; ++j) {
        const int col = n0 + wc * 64 + j * 16 + m16;
        const float bia = biasc[col];
        const float wrv = wrow[col];
#pragma unroll
        for (int i = 0; i < 4; ++i) {
            const int rb = m0 + wr * 64 + i * 16 + quad * 4;
#pragma unroll
            for (int r = 0; r < 4; ++r) {
                const int row = rb + r;
                xo[(size_t)row * GPo + col] = acc[i][j][r] + bia + tme[(size_t)row * T + t] * wrv;
            }
        }
    }
}

// ---------- per-step pointwise ----------
__global__ __launch_bounds__(64) void step_point(
    const float* __restrict__ xo, float* __restrict__ c, __hip_bfloat16* __restrict__ hb,
    float* __restrict__ tmp_h, float* __restrict__ tmp_dis, float* __restrict__ dist_out,
    int t)
{
    const int b = blockIdx.x;
    const int tid = threadIdx.x;
    const float* row = xo + (size_t)b * GPo;

    float fz[L], iz[L];
#pragma unroll
    for (int j = 0; j < L; ++j) { fz[j] = row[j]; iz[j] = row[L + j]; }

    float mx = fz[0];
#pragma unroll
    for (int j = 1; j < L; ++j) mx = fmaxf(mx, fz[j]);
    float s = 0.f;
#pragma unroll
    for (int j = 0; j < L; ++j) { fz[j] = expf(fz[j] - mx); s += fz[j]; }
    float fm[L];
    float run = 0.f;
#pragma unroll
    for (int j = 0; j < L; ++j) { run += fz[j]; fm[j] = run / s; }

    mx = iz[0];
#pragma unroll
    for (int j = 1; j < L; ++j) mx = fmaxf(mx, iz[j]);
    s = 0.f;
#pragma unroll
    for (int j = 0; j < L; ++j) { iz[j] = expf(iz[j] - mx); s += iz[j]; }
    float im[L];
    run = 0.f;
#pragma unroll
    for (int j = L - 1; j >= 0; --j) { run += iz[j]; im[j] = run / s; }

#pragma unroll
    for (int l = 0; l < L; ++l) {
        int hidx = l * 64 + tid;
        float ov = fm[l] * im[l];
        float fg = sigmoidf_(row[16 + l * 64 + tid]);
        float ig = sigmoidf_(row[16 + 512 + l * 64 + tid]);
        float og = sigmoidf_(row[16 + 1024 + l * 64 + tid]);
        float cg = tanhf(row[16 + 1536 + l * 64 + tid]);
        float cl = c[(size_t)b * H + hidx];
        float cn = ov * (fg * cl + ig * cg) + (fm[l] - ov) * cl + (im[l] - ov) * cg;
        float hn = og * tanhf(cn);
        c[(size_t)b * H + hidx] = cn;
        hb[(size_t)b * H + hidx] = __float2bfloat16(hn);
        if (t >= T - KW) tmp_h[((size_t)(t - (T - KW)) * B + b) * H + hidx] = hn;
    }
    if (tid == 0) {
        float a = 0.f;
#pragma unroll
        for (int j = 0; j < L; ++j) a += fm[j];
        float d = 1.0f - a / (float)L;
        dist_out[(size_t)t * B + b] = d;
        if (t >= T - KW) tmp_dis[(size_t)(t - (T - KW)) * B + b] = d;
    }
}

// ---------- post ----------
__global__ __launch_bounds__(128) void post_local(
    const float* __restrict__ tmp_h, const float* __restrict__ tmp_dis,
    float* __restrict__ mean_h, float* __restrict__ Ahk)
{
    const int b = blockIdx.x;
    const int tid = threadIdx.x;
    __shared__ float ld[KW];
    if (tid == 0) {
        float cd[KW];
        float run = 0.f;
        for (int k = 0; k < KW; ++k) { run += tmp_dis[(size_t)k * B + b]; cd[k] = run; }
        float mx = cd[0];
        for (int k = 1; k < KW; ++k) mx = fmaxf(mx, cd[k]);
        float s = 0.f;
        for (int k = 0; k < KW; ++k) { cd[k] = expf(cd[k] - mx); s += cd[k]; }
        for (int k = 0; k < KW; ++k) ld[k] = cd[k] / s;
    }
    __syncthreads();
    float ldr[KW];
#pragma unroll
    for (int k = 0; k < KW; ++k) ldr[k] = ld[k];
    for (int h = tid; h < H; h += 128) {
        float s = 0.f;
#pragma unroll
        for (int k = 0; k < KW; ++k) {
            float v = tmp_h[((size_t)k * B + b) * H + h] * ldr[k];
            s += v;
            Ahk[(size_t)b * (H * KW) + (size_t)h * KW + k] = v;
        }
        mean_h[(size_t)b * H + h] = s * (1.0f / KW);
    }
}

__global__ void theme1_k(const float* __restrict__ mean_h, const float* __restrict__ Ws,
                         const float* __restrict__ bs, float* __restrict__ t1)
{
    int idx = blockIdx.x * blockDim.x + threadIdx.x;
    if (idx >= B * HS) return;
    int b = idx / HS, j = idx % HS;
    float s = bs[j];
    const float* mh = mean_h + (size_t)b * H;
    for (int h = 0; h < H; ++h) s += mh[h] * Ws[(size_t)h * HS + j];
    t1[idx] = fmaxf(s, 0.f);
}

__global__ void theme2_k(const float* __restrict__ t1, const float* __restrict__ Wrs,
                         const float* __restrict__ brs, float* __restrict__ theme)
{
    int idx = blockIdx.x * blockDim.x + threadIdx.x;
    if (idx >= B * H) return;
    int b = idx / H, o = idx % H;
    float s = brs[o];
    const float* tv = t1 + (size_t)b * HS;
    for (int j = 0; j < HS; ++j) s += tv[j] * Wrs[(size_t)j * H + o];
    theme[idx] = sigmoidf_(s);
}

__global__ __launch_bounds__(256) void conv_gemm(
    const float* __restrict__ Ahk, const float* __restrict__ CWt,
    const float* __restrict__ conv_b, const float* __restrict__ theme,
    float* __restrict__ out0)
{
    __shared__ float As[16][68];
    __shared__ float Bs[16][64];
    const int tid = threadIdx.x;
    const int n0 = blockIdx.x * 64, m0 = blockIdx.y * 64;
    const int am = tid >> 2, ak = (tid & 3) << 2;
    const int bkr = tid >> 4, bn = (tid & 15) << 2;
    const int tn = (tid & 15) << 2, tm = (tid >> 4) << 2;
    float acc[4][4] = {};
    for (int k0 = 0; k0 < H * KW; k0 += 16) {
        float4 av = *(const float4*)(Ahk + (size_t)(m0 + am) * (H * KW) + k0 + ak);
        As[ak + 0][am] = av.x; As[ak + 1][am] = av.y; As[ak + 2][am] = av.z; As[ak + 3][am] = av.w;
        *(float4*)&Bs[bkr][bn] = *(const float4*)(CWt + (size_t)(k0 + bkr) * H + n0 + bn);
        __syncthreads();
#pragma unroll
        for (int k = 0; k < 16; ++k) {
            float4 a4 = *(const float4*)&As[k][tm];
            float4 b4 = *(const float4*)&Bs[k][tn];
            acc[0][0] += a4.x * b4.x; acc[0][1] += a4.x * b4.y; acc[0][2] += a4.x * b4.z; acc[0][3] += a4.x * b4.w;
            acc[1][0] += a4.y * b4.x; acc[1][1] += a4.y * b4.y; acc[1][2] += a4.y * b4.z; acc[1][3] += a4.y * b4.w;
            acc[2][0] += a4.z * b4.x; acc[2][1] += a4.z * b4.y; acc[2][2] += a4.z * b4.z; acc[2][3] += a4.z * b4.w;
            acc[3][0] += a4.w * b4.x; acc[3][1] += a4.w * b4.y; acc[3][2] += a4.w * b4.z; acc[3][3] += a4.w * b4.w;
        }
        __syncthreads();
    }
    float4 cb4 = *(const float4*)(conv_b + n0 + tn);
#pragma unroll
    for (int r = 0; r < 4; ++r) {
        int m = m0 + tm + r;
        float4 th4 = *(const float4*)(theme + (size_t)m * H + n0 + tn);
        float4 o4;
        o4.x = th4.x * (acc[r][0] + cb4.x);
        o4.y = th4.y * (acc[r][1] + cb4.y);
        o4.z = th4.z * (acc[r][2] + cb4.z);
        o4.w = th4.w * (acc[r][3] + cb4.w);
        *(float4*)(out0 + (size_t)m * H + n0 + tn) = o4;
    }
}

} // namespace

extern "C" void kernel_launch(void* const* d_in, const int* in_sizes, int n_in,
                              void* d_out, int out_size, void* d_ws, size_t ws_size,
                              hipStream_t stream)
{
    (void)in_sizes; (void)n_in; (void)out_size; (void)ws_size;
    const float* x      = (const float*)d_in[0];
    const float* tme    = (const float*)d_in[1];
    const float* Wk     = (const float*)d_in[2];
    const float* bk     = (const float*)d_in[3];
    const float* Wr     = (const float*)d_in[4];
    const float* br     = (const float*)d_in[5];
    const float* Ws     = (const float*)d_in[6];
    const float* bs     = (const float*)d_in[7];
    const float* Wrs    = (const float*)d_in[8];
    const float* brs    = (const float*)d_in[9];
    const float* conv_w = (const float*)d_in[10];
    const float* conv_b = (const float*)d_in[11];

    float* out0 = (float*)d_out;
    float* dist_out = out0 + (size_t)B * H;   // distance (T, B)

    // workspace carve (bytes, all 16B-aligned sizes); total ~198 MB
    char* w = (char*)d_ws;
    __hip_bfloat16* WcT = (__hip_bfloat16*)w; w += (size_t)GPo * KIN * 2;
    float* wrow   = (float*)w; w += (size_t)GPo * 4;
    float* biasc  = (float*)w; w += (size_t)GPo * 4;
    __hip_bfloat16* xb = (__hip_bfloat16*)w; w += (size_t)B * T * F * 2;
    float* xo     = (float*)w; w += (size_t)B * GPo * 4;
    float* c      = (float*)w; w += (size_t)B * H * 4;
    __hip_bfloat16* hb = (__hip_bfloat16*)w; w += (size_t)B * H * 2;
    float* tmp_h  = (float*)w; w += (size_t)KW * B * H * 4;
    float* tmp_ds = (float*)w; w += (size_t)KW * B * 4;
    float* mean_h = (float*)w; w += (size_t)B * H * 4;
    float* t1     = (float*)w; w += (size_t)B * HS * 4;
    float* theme  = (float*)w; w += (size_t)B * H * 4;
    float* Ahk    = (float*)w; w += (size_t)B * H * KW * 4;
    float* CWt    = (float*)w; w += (size_t)H * KW * H * 4;

    hipMemsetAsync(c, 0, (size_t)B * H * sizeof(float), stream);
    hipMemsetAsync(hb, 0, (size_t)B * H * sizeof(__hip_bfloat16), stream);

    {
        int total = GPo * KIN + 2 * GPo;
        prep_weights<<<(total + 255) / 256, 256, 0, stream>>>(Wk, bk, Wr, br, WcT, wrow, biasc);
    }
    convert_x<<<((B * T * F / 4) + 255) / 256, 256, 0, stream>>>(x, xb);
    prep_cwt<<<(H * H * KW + 255) / 256, 256, 0, stream>>>(conv_w, CWt);

    for (int t = 0; t < T; ++t) {
        step_gemm_mfma<<<dim3(GPo / 128, B / 128), 256, 0, stream>>>(xb, hb, WcT, wrow, biasc, tme, xo, t);
        step_point<<<B, 64, 0, stream>>>(xo, c, hb, tmp_h, tmp_ds, dist_out, t);
    }

    post_local<<<B, 128, 0, stream>>>(tmp_h, tmp_ds, mean_h, Ahk);
    theme1_k<<<(B * HS + 255) / 256, 256, 0, stream>>>(mean_h, Ws, bs, t1);
    theme2_k<<<(B * H + 255) / 256, 256, 0, stream>>>(t1, Wrs, brs, theme);
    conv_gemm<<<dim3(H / 64, B / 64), 256, 0, stream>>>(Ahk, CWt, conv_b, theme, out0);
}

// Round 3
// 3313.581 us; speedup vs baseline: 4.2186x; 1.4147x over previous
//
#include <hip/hip_runtime.h>
#include <hip/hip_bf16.h>
#include <cstddef>
#include <cstdint>

namespace {

constexpr int B = 2048, T = 128, F = 128, H = 512, L = 8, KW = 10;
constexpr int GATES = 2064;
constexpr int NG = 2048;    // gate columns in the big GEMM (permuted)
constexpr int KIN = 640;    // F + H
constexpr int HS = 85;      // H // 6
constexpr int RC = H * KW;  // 5120, conv reduction dim

typedef __attribute__((ext_vector_type(8))) short short8;
typedef __attribute__((ext_vector_type(4))) float f32x4;

__device__ __forceinline__ float sigmoidf_(float x) { return 1.0f / (1.0f + expf(-x)); }

__device__ __forceinline__ void gl_lds16(const void* g, void* l) {
    __builtin_amdgcn_global_load_lds(
        (const __attribute__((address_space(1))) unsigned int*)g,
        (__attribute__((address_space(3))) unsigned int*)l,
        16, 0, 0);
}

// Column permutation: GEMM col -> (gate j, h). Within a 128-col N-tile:
// wc=c>>6, j=(c>>4)&3, m16=c&15 -> h = nt*32 + wc*16 + m16, orig_n = 16 + j*512 + h.
// This puts the 4 gates of one h into one lane's acc[i][0..3].
__global__ void prep_weights(const float* __restrict__ Wk, const float* __restrict__ bk,
                             const float* __restrict__ Wr, const float* __restrict__ br,
                             __hip_bfloat16* __restrict__ WgT, __hip_bfloat16* __restrict__ W16T,
                             float* __restrict__ biasg, float* __restrict__ wrowg,
                             float* __restrict__ bias16, float* __restrict__ wrow16)
{
    int idx = blockIdx.x * blockDim.x + threadIdx.x;
    const int NW = NG * KIN;
    if (idx < NW) {
        int col = idx / KIN, k = idx % KIN;
        int nt = col >> 7, cc = col & 127;
        int wcx = cc >> 6, j = (cc >> 4) & 3, m16x = cc & 15;
        int n = 16 + j * 512 + (nt * 32 + wcx * 16 + m16x);
        float v = (k < F) ? Wk[(size_t)k * GATES + n] : Wr[(size_t)(k - F) * GATES + n];
        WgT[idx] = __float2bfloat16(v);
    } else if (idx < NW + 16 * KIN) {
        int r = idx - NW;
        int n = r / KIN, k = r % KIN;
        float v = (k < F) ? Wk[(size_t)k * GATES + n] : Wr[(size_t)(k - F) * GATES + n];
        W16T[r] = __float2bfloat16(v);
    } else if (idx < NW + 16 * KIN + NG) {
        int col = idx - NW - 16 * KIN;
        int nt = col >> 7, cc = col & 127;
        int n = 16 + ((cc >> 4) & 3) * 512 + (nt * 32 + (cc >> 6) * 16 + (cc & 15));
        biasg[col] = bk[n] + br[n];
    } else if (idx < NW + 16 * KIN + 2 * NG) {
        int col = idx - NW - 16 * KIN - NG;
        int nt = col >> 7, cc = col & 127;
        int n = 16 + ((cc >> 4) & 3) * 512 + (nt * 32 + (cc >> 6) * 16 + (cc & 15));
        wrowg[col] = Wk[(size_t)F * GATES + n] + Wr[(size_t)H * GATES + n];
    } else if (idx < NW + 16 * KIN + 2 * NG + 16) {
        int n = idx - NW - 16 * KIN - 2 * NG;
        bias16[n] = bk[n] + br[n];
    } else if (idx < NW + 16 * KIN + 2 * NG + 32) {
        int n = idx - NW - 16 * KIN - 2 * NG - 16;
        wrow16[n] = Wk[(size_t)F * GATES + n] + Wr[(size_t)H * GATES + n];
    }
}

__global__ void convert_x(const float* __restrict__ x, __hip_bfloat16* __restrict__ xb) {
    int i = blockIdx.x * blockDim.x + threadIdx.x;
    size_t o = (size_t)i * 4;
    if (o >= (size_t)B * T * F) return;
    float4 v = *(const float4*)(x + o);
    xb[o + 0] = __float2bfloat16(v.x);
    xb[o + 1] = __float2bfloat16(v.y);
    xb[o + 2] = __float2bfloat16(v.z);
    xb[o + 3] = __float2bfloat16(v.w);
}

__global__ void prep_convw(const float* __restrict__ conv_w, __hip_bfloat16* __restrict__ CWb) {
    int i = blockIdx.x * blockDim.x + threadIdx.x;
    if (i >= H * RC / 4) return;  // treat as flat; conv_w[o][h][k] is already B^T layout [o][r]
    size_t o = (size_t)i * 4;
    float4 v = *(const float4*)(conv_w + o);
    CWb[o + 0] = __float2bfloat16(v.x);
    CWb[o + 1] = __float2bfloat16(v.y);
    CWb[o + 2] = __float2bfloat16(v.z);
    CWb[o + 3] = __float2bfloat16(v.w);
}

// ---------- the fused step: GEMM + logits + softmax-cumsum + cell update ----------
// grid (16 n-tiles, 32 m-tiles), 256 threads, M-tile 64 x N-tile 128, BK 32.
// Wave tile 32(M) x 64(N): acc[i][j] j = gate index after permutation.
__global__ __launch_bounds__(256, 2) void step_fused(
    const __hip_bfloat16* __restrict__ xb, const __hip_bfloat16* __restrict__ hin,
    __hip_bfloat16* __restrict__ hout,
    const __hip_bfloat16* __restrict__ WgT, const __hip_bfloat16* __restrict__ W16T,
    const float* __restrict__ biasg, const float* __restrict__ wrowg,
    const float* __restrict__ bias16, const float* __restrict__ wrow16,
    const float* __restrict__ tme, float* __restrict__ c,
    float* __restrict__ tmp_h, float* __restrict__ tmp_dis, float* __restrict__ dist_out,
    int t)
{
    __shared__ __align__(16) unsigned short As[64 * 32];    // 4 KB
    __shared__ __align__(16) unsigned short Bs[128 * 32];   // 8 KB
    __shared__ __align__(16) unsigned short W16s[16 * 648]; // 20.25 KB (pad 648: 2-way banks)
    __shared__ float logitS[64 * 17];                        // 4.25 KB
    __shared__ float fmimS[64 * 16];                         // 4 KB

    const int tid = threadIdx.x;
    const int wave = tid >> 6, lane = tid & 63;
    const int wr = wave >> 1, wc = wave & 1;
    const int quad = lane >> 4, m16 = lane & 15;
    const int nt = blockIdx.x;
    const int m0 = blockIdx.y * 64;

    // stage W16T (640x16 logits weight) into LDS once; first k-iter barrier covers it
    for (int i = tid; i < 16 * 80; i += 256) {
        int n = i / 80, k8 = (i % 80) * 8;
        *(short8*)&W16s[n * 648 + k8] = *(const short8*)(W16T + n * KIN + k8);
    }

    f32x4 acc[2][4] = {};
    f32x4 acc16[2] = {};

    const int arow = tid >> 2, akk = (tid & 3) * 8;
    for (int k0 = 0; k0 < KIN; k0 += 32) {
        const __hip_bfloat16* asrc = (k0 < F)
            ? xb + ((size_t)(m0 + arow) * T + t) * F + (k0 + akk)
            : hin + (size_t)(m0 + arow) * H + (k0 - F + akk);
        gl_lds16(asrc, (char*)As + tid * 16);
#pragma unroll
        for (int r = 0; r < 2; ++r) {
            int o = r * 4096 + tid * 16;
            int brow = o >> 6;
            int bkk = ((o >> 4) & 3) * 8;
            gl_lds16(WgT + (size_t)(nt * 128 + brow) * KIN + k0 + bkk, (char*)Bs + o);
        }
        __syncthreads();

        short8 av[2], bv[4];
#pragma unroll
        for (int i = 0; i < 2; ++i)
            av[i] = *(const short8*)&As[(wr * 32 + i * 16 + m16) * 32 + quad * 8];
#pragma unroll
        for (int j = 0; j < 4; ++j)
            bv[j] = *(const short8*)&Bs[(wc * 64 + j * 16 + m16) * 32 + quad * 8];
#pragma unroll
        for (int i = 0; i < 2; ++i)
#pragma unroll
            for (int j = 0; j < 4; ++j)
                acc[i][j] = __builtin_amdgcn_mfma_f32_16x16x32_bf16(av[i], bv[j], acc[i][j], 0, 0, 0);
        if (wc == 0) {
            short8 wv = *(const short8*)&W16s[m16 * 648 + k0 + quad * 8];
            acc16[0] = __builtin_amdgcn_mfma_f32_16x16x32_bf16(av[0], wv, acc16[0], 0, 0, 0);
            acc16[1] = __builtin_amdgcn_mfma_f32_16x16x32_bf16(av[1], wv, acc16[1], 0, 0, 0);
        }
        __syncthreads();
    }

    // ---- logits -> LDS (wc==0 waves cover all 64 rows x 16 logits)
    if (wc == 0) {
#pragma unroll
        for (int i = 0; i < 2; ++i)
#pragma unroll
            for (int r = 0; r < 4; ++r)
                logitS[(wr * 32 + i * 16 + quad * 4 + r) * 17 + m16] = acc16[i][r];
    }
    __syncthreads();

    // ---- per-row softmax-cumsum (fm l2r, im r2l), dist
    if (tid < 64) {
        int m = m0 + tid;
        float dt = tme[(size_t)m * T + t];
        float z[16];
#pragma unroll
        for (int n = 0; n < 16; ++n) z[n] = logitS[tid * 17 + n] + bias16[n] + dt * wrow16[n];
        float mx = z[0];
#pragma unroll
        for (int j = 1; j < L; ++j) mx = fmaxf(mx, z[j]);
        float e[L], s = 0.f;
#pragma unroll
        for (int j = 0; j < L; ++j) { e[j] = expf(z[j] - mx); s += e[j]; }
        float run = 0.f, fsum = 0.f;
#pragma unroll
        for (int j = 0; j < L; ++j) { run += e[j]; float fmv = run / s; fmimS[tid * 16 + j] = fmv; fsum += fmv; }
        mx = z[L];
#pragma unroll
        for (int j = 1; j < L; ++j) mx = fmaxf(mx, z[L + j]);
        s = 0.f;
#pragma unroll
        for (int j = 0; j < L; ++j) { e[j] = expf(z[L + j] - mx); s += e[j]; }
        run = 0.f;
#pragma unroll
        for (int j = L - 1; j >= 0; --j) { run += e[j]; fmimS[tid * 16 + 8 + j] = run / s; }
        if (nt == 0) {
            float d = 1.0f - fsum / (float)L;
            dist_out[(size_t)t * B + m] = d;
            if (t >= T - KW) tmp_dis[(size_t)(t - (T - KW)) * B + m] = d;
        }
    }
    __syncthreads();

    // ---- gates + cell update in registers
    const int hcol = nt * 32 + wc * 16 + m16;
    const int lidx = hcol >> 6;
    float bj[4], wj[4];
#pragma unroll
    for (int j = 0; j < 4; ++j) {
        int col = nt * 128 + wc * 64 + j * 16 + m16;
        bj[j] = biasg[col];
        wj[j] = wrowg[col];
    }
#pragma unroll
    for (int i = 0; i < 2; ++i) {
#pragma unroll
        for (int r = 0; r < 4; ++r) {
            int rl = wr * 32 + i * 16 + quad * 4 + r;
            int m = m0 + rl;
            float dt = tme[(size_t)m * T + t];
            float fmv = fmimS[rl * 16 + lidx];
            float imv = fmimS[rl * 16 + 8 + lidx];
            float fg = sigmoidf_(acc[i][0][r] + bj[0] + dt * wj[0]);
            float ig = sigmoidf_(acc[i][1][r] + bj[1] + dt * wj[1]);
            float og = sigmoidf_(acc[i][2][r] + bj[2] + dt * wj[2]);
            float ci = tanhf(acc[i][3][r] + bj[3] + dt * wj[3]);
            float ov = fmv * imv;
            size_t off = (size_t)m * H + hcol;
            float cl = c[off];
            float cn = ov * (fg * cl + ig * ci) + (fmv - ov) * cl + (imv - ov) * ci;
            float hn = og * tanhf(cn);
            c[off] = cn;
            hout[off] = __float2bfloat16(hn);
            if (t >= T - KW) tmp_h[((size_t)(t - (T - KW)) * B + m) * H + hcol] = hn;
        }
    }
}

// ---------- post ----------
__global__ __launch_bounds__(128) void post_local(
    const float* __restrict__ tmp_h, const float* __restrict__ tmp_dis,
    float* __restrict__ mean_h, __hip_bfloat16* __restrict__ Ahk)
{
    const int b = blockIdx.x;
    const int tid = threadIdx.x;
    __shared__ float ld[KW];
    if (tid == 0) {
        float cd[KW];
        float run = 0.f;
        for (int k = 0; k < KW; ++k) { run += tmp_dis[(size_t)k * B + b]; cd[k] = run; }
        float mx = cd[0];
        for (int k = 1; k < KW; ++k) mx = fmaxf(mx, cd[k]);
        float s = 0.f;
        for (int k = 0; k < KW; ++k) { cd[k] = expf(cd[k] - mx); s += cd[k]; }
        for (int k = 0; k < KW; ++k) ld[k] = cd[k] / s;
    }
    __syncthreads();
    float ldr[KW];
#pragma unroll
    for (int k = 0; k < KW; ++k) ldr[k] = ld[k];
    for (int h = tid; h < H; h += 128) {
        float s = 0.f;
#pragma unroll
        for (int k = 0; k < KW; ++k) {
            float v = tmp_h[((size_t)k * B + b) * H + h] * ldr[k];
            s += v;
            Ahk[(size_t)b * RC + h * KW + k] = __float2bfloat16(v);
        }
        mean_h[(size_t)b * H + h] = s * (1.0f / KW);
    }
}

__global__ void theme1_k(const float* __restrict__ mean_h, const float* __restrict__ Ws,
                         const float* __restrict__ bs, float* __restrict__ t1)
{
    int idx = blockIdx.x * blockDim.x + threadIdx.x;
    if (idx >= B * HS) return;
    int b = idx / HS, j = idx % HS;
    float s = bs[j];
    const float* mh = mean_h + (size_t)b * H;
    for (int h = 0; h < H; ++h) s += mh[h] * Ws[(size_t)h * HS + j];
    t1[idx] = fmaxf(s, 0.f);
}

__global__ void theme2_k(const float* __restrict__ t1, const float* __restrict__ Wrs,
                         const float* __restrict__ brs, float* __restrict__ theme)
{
    int idx = blockIdx.x * blockDim.x + threadIdx.x;
    if (idx >= B * H) return;
    int b = idx / H, o = idx % H;
    float s = brs[o];
    const float* tv = t1 + (size_t)b * HS;
    for (int j = 0; j < HS; ++j) s += tv[j] * Wrs[(size_t)j * H + o];
    theme[idx] = sigmoidf_(s);
}

// out0[b][o] = theme[b][o]*(sum_r Ahk[b][r]*CWb[o][r] + conv_b[o]); bf16 MFMA, K=5120
__global__ __launch_bounds__(256) void conv_mfma(
    const __hip_bfloat16* __restrict__ Ahk, const __hip_bfloat16* __restrict__ CWb,
    const float* __restrict__ conv_b, const float* __restrict__ theme,
    float* __restrict__ out0)
{
    __shared__ __align__(16) unsigned short As2[128 * 32];
    __shared__ __align__(16) unsigned short Bs2[128 * 32];
    const int tid = threadIdx.x;
    const int wave = tid >> 6, lane = tid & 63;
    const int wr = wave >> 1, wc = wave & 1;
    const int quad = lane >> 4, m16 = lane & 15;
    const int m0 = blockIdx.y * 128, n0 = blockIdx.x * 128;

    f32x4 acc[4][4] = {};
    for (int k0 = 0; k0 < RC; k0 += 32) {
#pragma unroll
        for (int r = 0; r < 2; ++r) {
            int o = r * 4096 + wave * 1024 + lane * 16;
            int row = o >> 6;
            int kg = k0 + ((o >> 4) & 3) * 8;
            gl_lds16(Ahk + (size_t)(m0 + row) * RC + kg, (char*)As2 + o);
            gl_lds16(CWb + (size_t)(n0 + row) * RC + kg, (char*)Bs2 + o);
        }
        __syncthreads();
        short8 av[4], bv[4];
#pragma unroll
        for (int i = 0; i < 4; ++i)
            av[i] = *(const short8*)&As2[(wr * 64 + i * 16 + m16) * 32 + quad * 8];
#pragma unroll
        for (int j = 0; j < 4; ++j)
            bv[j] = *(const short8*)&Bs2[(wc * 64 + j * 16 + m16) * 32 + quad * 8];
#pragma unroll
        for (int i = 0; i < 4; ++i)
#pragma unroll
            for (int j = 0; j < 4; ++j)
                acc[i][j] = __builtin_amdgcn_mfma_f32_16x16x32_bf16(av[i], bv[j], acc[i][j], 0, 0, 0);
        __syncthreads();
    }
#pragma unroll
    for (int j = 0; j < 4; ++j) {
        const int col = n0 + wc * 64 + j * 16 + m16;
        const float cb = conv_b[col];
#pragma unroll
        for (int i = 0; i < 4; ++i) {
            const int rb = m0 + wr * 64 + i * 16 + quad * 4;
#pragma unroll
            for (int r = 0; r < 4; ++r) {
                const int row = rb + r;
                out0[(size_t)row * H + col] = theme[(size_t)row * H + col] * (acc[i][j][r] + cb);
            }
        }
    }
}

} // namespace

extern "C" void kernel_launch(void* const* d_in, const int* in_sizes, int n_in,
                              void* d_out, int out_size, void* d_ws, size_t ws_size,
                              hipStream_t stream)
{
    (void)in_sizes; (void)n_in; (void)out_size; (void)ws_size;
    const float* x      = (const float*)d_in[0];
    const float* tme    = (const float*)d_in[1];
    const float* Wk     = (const float*)d_in[2];
    const float* bk     = (const float*)d_in[3];
    const float* Wr     = (const float*)d_in[4];
    const float* br     = (const float*)d_in[5];
    const float* Ws     = (const float*)d_in[6];
    const float* bs     = (const float*)d_in[7];
    const float* Wrs    = (const float*)d_in[8];
    const float* brs    = (const float*)d_in[9];
    const float* conv_w = (const float*)d_in[10];
    const float* conv_b = (const float*)d_in[11];

    float* out0 = (float*)d_out;
    float* dist_out = out0 + (size_t)B * H;

    // workspace carve (~155 MB)
    char* w = (char*)d_ws;
    __hip_bfloat16* WgT  = (__hip_bfloat16*)w; w += (size_t)NG * KIN * 2;
    __hip_bfloat16* W16T = (__hip_bfloat16*)w; w += (size_t)16 * KIN * 2;
    __hip_bfloat16* xb   = (__hip_bfloat16*)w; w += (size_t)B * T * F * 2;
    __hip_bfloat16* CWb  = (__hip_bfloat16*)w; w += (size_t)H * RC * 2;
    __hip_bfloat16* Ahk  = (__hip_bfloat16*)w; w += (size_t)B * RC * 2;
    __hip_bfloat16* hb0  = (__hip_bfloat16*)w; w += (size_t)B * H * 2;
    __hip_bfloat16* hb1  = (__hip_bfloat16*)w; w += (size_t)B * H * 2;
    float* biasg  = (float*)w; w += (size_t)NG * 4;
    float* wrowg  = (float*)w; w += (size_t)NG * 4;
    float* bias16 = (float*)w; w += 64;
    float* wrow16 = (float*)w; w += 64;
    float* c      = (float*)w; w += (size_t)B * H * 4;
    float* tmp_h  = (float*)w; w += (size_t)KW * B * H * 4;
    float* tmp_ds = (float*)w; w += (size_t)KW * B * 4;
    float* mean_h = (float*)w; w += (size_t)B * H * 4;
    float* t1     = (float*)w; w += (size_t)B * HS * 4;
    float* theme  = (float*)w; w += (size_t)B * H * 4;

    hipMemsetAsync(c, 0, (size_t)B * H * sizeof(float), stream);
    hipMemsetAsync(hb0, 0, (size_t)B * H * sizeof(__hip_bfloat16), stream);

    {
        int total = NG * KIN + 16 * KIN + 2 * NG + 32;
        prep_weights<<<(total + 255) / 256, 256, 0, stream>>>(
            Wk, bk, Wr, br, WgT, W16T, biasg, wrowg, bias16, wrow16);
    }
    convert_x<<<((B * T * F / 4) + 255) / 256, 256, 0, stream>>>(x, xb);
    prep_convw<<<((H * RC / 4) + 255) / 256, 256, 0, stream>>>(conv_w, CWb);

    for (int t = 0; t < T; ++t) {
        const __hip_bfloat16* hin = (t & 1) ? hb1 : hb0;
        __hip_bfloat16* hout = (t & 1) ? hb0 : hb1;
        step_fused<<<dim3(NG / 128, B / 64), 256, 0, stream>>>(
            xb, hin, hout, WgT, W16T, biasg, wrowg, bias16, wrow16,
            tme, c, tmp_h, tmp_ds, dist_out, t);
    }

    post_local<<<B, 128, 0, stream>>>(tmp_h, tmp_ds, mean_h, Ahk);
    theme1_k<<<(B * HS + 255) / 256, 256, 0, stream>>>(mean_h, Ws, bs, t1);
    theme2_k<<<(B * H + 255) / 256, 256, 0, stream>>>(t1, Wrs, brs, theme);
    conv_mfma<<<dim3(H / 128, B / 128), 256, 0, stream>>>(Ahk, CWb, conv_b, theme, out0);
}

// Round 5
// 2853.468 us; speedup vs baseline: 4.8988x; 1.1612x over previous
//
#include <hip/hip_runtime.h>
#include <hip/hip_bf16.h>
#include <cstddef>
#include <cstdint>

namespace {

constexpr int B = 2048, T = 128, F = 128, H = 512, L = 8, KW = 10;
constexpr int GATES = 2064;
constexpr int NG = 2048;    // gate columns (permuted)
constexpr int KIN = 640;    // F + H
constexpr int HS = 85;      // H // 6
constexpr int RC = H * KW;  // 5120
constexpr int KS = 8;       // conv split-K slices

typedef __attribute__((ext_vector_type(8))) short short8;
typedef __attribute__((ext_vector_type(4))) float f32x4;

__device__ __forceinline__ float sigmoidf_(float x) { return 1.0f / (1.0f + expf(-x)); }

__device__ __forceinline__ void gl_lds16(const void* g, void* l) {
    __builtin_amdgcn_global_load_lds(
        (const __attribute__((address_space(1))) unsigned int*)g,
        (__attribute__((address_space(3))) unsigned int*)l,
        16, 0, 0);
}

// ---------- prep ----------
// WgT[col][k] bf16 via LDS transpose. col permutation: within 128-col tile,
// col = wc*64 + j*16 + m16 -> orig n = 16 + j*512 + nt*32 + wc*16 + m16.
__global__ __launch_bounds__(256) void prep_wgt(
    const float* __restrict__ Wk, const float* __restrict__ Wr,
    __hip_bfloat16* __restrict__ WgT)
{
    __shared__ float tile[64 * 65];
    const int tid = threadIdx.x;
    const int c0 = blockIdx.x * 64, k0 = blockIdx.y * 64;
#pragma unroll
    for (int rep = 0; rep < 16; ++rep) {
        int e = rep * 256 + tid;
        int kl = e >> 6, cl = e & 63;
        int col = c0 + cl;
        int nt = col >> 7, cc = col & 127;
        int n = 16 + ((cc >> 4) & 3) * 512 + nt * 32 + ((cc >> 6) & 1) * 16 + (cc & 15);
        int k = k0 + kl;
        tile[kl * 65 + cl] = (k < F) ? Wk[(size_t)k * GATES + n] : Wr[(size_t)(k - F) * GATES + n];
    }
    __syncthreads();
    const int cl = tid >> 2, q = tid & 3;
    unsigned short buf[16];
#pragma unroll
    for (int i = 0; i < 16; ++i) {
        float f = tile[(q * 16 + i) * 65 + cl];
        __hip_bfloat16 bv = __float2bfloat16(f);
        buf[i] = *(unsigned short*)&bv;
    }
    unsigned short* dst = (unsigned short*)WgT + (size_t)(c0 + cl) * KIN + k0 + q * 16;
    *(short8*)dst = *(short8*)&buf[0];
    *(short8*)(dst + 8) = *(short8*)&buf[8];
}

__global__ void prep_small(const float* __restrict__ Wk, const float* __restrict__ bk,
                           const float* __restrict__ Wr, const float* __restrict__ br,
                           __hip_bfloat16* __restrict__ W16T,
                           float* __restrict__ biasg, float* __restrict__ wrowg,
                           float* __restrict__ bias16, float* __restrict__ wrow16)
{
    const int total = 16 * KIN + 2 * NG + 32;
    for (int idx = threadIdx.x; idx < total; idx += 256) {
        if (idx < 16 * KIN) {
            int n = idx / KIN, k = idx % KIN;
            float v = (k < F) ? Wk[(size_t)k * GATES + n] : Wr[(size_t)(k - F) * GATES + n];
            W16T[idx] = __float2bfloat16(v);
        } else if (idx < 16 * KIN + NG) {
            int col = idx - 16 * KIN;
            int nt = col >> 7, cc = col & 127;
            int n = 16 + ((cc >> 4) & 3) * 512 + nt * 32 + ((cc >> 6) & 1) * 16 + (cc & 15);
            biasg[col] = bk[n] + br[n];
        } else if (idx < 16 * KIN + 2 * NG) {
            int col = idx - 16 * KIN - NG;
            int nt = col >> 7, cc = col & 127;
            int n = 16 + ((cc >> 4) & 3) * 512 + nt * 32 + ((cc >> 6) & 1) * 16 + (cc & 15);
            wrowg[col] = Wk[(size_t)F * GATES + n] + Wr[(size_t)H * GATES + n];
        } else if (idx < 16 * KIN + 2 * NG + 16) {
            int n = idx - 16 * KIN - 2 * NG;
            bias16[n] = bk[n] + br[n];
        } else {
            int n = idx - 16 * KIN - 2 * NG - 16;
            wrow16[n] = Wk[(size_t)F * GATES + n] + Wr[(size_t)H * GATES + n];
        }
    }
}

__global__ void convert_x(const float* __restrict__ x, __hip_bfloat16* __restrict__ xb) {
    int i = blockIdx.x * blockDim.x + threadIdx.x;
    size_t o = (size_t)i * 4;
    if (o >= (size_t)B * T * F) return;
    float4 v = *(const float4*)(x + o);
    xb[o + 0] = __float2bfloat16(v.x);
    xb[o + 1] = __float2bfloat16(v.y);
    xb[o + 2] = __float2bfloat16(v.z);
    xb[o + 3] = __float2bfloat16(v.w);
}

__global__ void prep_convw(const float* __restrict__ conv_w, __hip_bfloat16* __restrict__ CWb) {
    int i = blockIdx.x * blockDim.x + threadIdx.x;
    if (i >= H * RC / 4) return;
    size_t o = (size_t)i * 4;
    float4 v = *(const float4*)(conv_w + o);
    CWb[o + 0] = __float2bfloat16(v.x);
    CWb[o + 1] = __float2bfloat16(v.y);
    CWb[o + 2] = __float2bfloat16(v.z);
    CWb[o + 3] = __float2bfloat16(v.w);
}

// ---------- fused step: GEMM + logits + softmax-cumsum + cell update ----------
// grid (16 nt, 32 mt), 256 threads. M-tile 64, N-tile 128, BK 64 (10 k-iters).
__global__ __launch_bounds__(256, 2) void step_fused(
    const __hip_bfloat16* __restrict__ xb, const __hip_bfloat16* __restrict__ hin,
    __hip_bfloat16* __restrict__ hout,
    const __hip_bfloat16* __restrict__ WgT, const __hip_bfloat16* __restrict__ W16T,
    const float* __restrict__ biasg, const float* __restrict__ wrowg,
    const float* __restrict__ bias16, const float* __restrict__ wrow16,
    const float* __restrict__ tme, float* __restrict__ c,
    __hip_bfloat16* __restrict__ tmp_h, float* __restrict__ tmp_dis,
    float* __restrict__ dist_out, int t)
{
    __shared__ __align__(16) unsigned short As[64 * 64];    // 8 KB
    __shared__ __align__(16) unsigned short Bs[128 * 64];   // 16 KB
    __shared__ __align__(16) unsigned short W16s[16 * 648]; // 20.25 KB
    __shared__ float logitS[64 * 17];
    __shared__ float fmimS[64 * 16];

    const int tid = threadIdx.x;
    const int wave = tid >> 6, lane = tid & 63;
    const int wr = wave >> 1, wc = wave & 1;
    const int quad = lane >> 4, m16 = lane & 15;
    const int nt = blockIdx.x;
    const int m0 = blockIdx.y * 64;

    // stage W16T; first k-iter barrier covers it
    for (int i = tid; i < 16 * 80; i += 256) {
        int n = i / 80, k8 = (i % 80) * 8;
        *(short8*)&W16s[n * 648 + k8] = *(const short8*)((const unsigned short*)W16T + n * KIN + k8);
    }

    f32x4 acc[2][4] = {};
    f32x4 acc16[2] = {};

    for (int k0 = 0; k0 < KIN; k0 += 64) {
        // A: 64 rows x 64 k; source-side XOR swizzle (dest stays lane-contiguous)
#pragma unroll
        for (int p = 0; p < 2; ++p) {
            int o = p * 4096 + tid * 16;
            int row = o >> 7, slot = (o >> 4) & 7;
            int kg = k0 + (slot ^ (row & 7)) * 8;
            const __hip_bfloat16* src = (k0 < F)
                ? xb + ((size_t)(m0 + row) * T + t) * F + kg
                : hin + (size_t)(m0 + row) * H + (kg - F);
            gl_lds16(src, (char*)As + o);
        }
        // B: 128 rows x 64 k
#pragma unroll
        for (int p = 0; p < 4; ++p) {
            int o = p * 4096 + tid * 16;
            int row = o >> 7, slot = (o >> 4) & 7;
            int kg = k0 + (slot ^ (row & 7)) * 8;
            gl_lds16((const unsigned short*)WgT + (size_t)(nt * 128 + row) * KIN + kg,
                     (char*)Bs + o);
        }
        __syncthreads();

#pragma unroll
        for (int c2 = 0; c2 < 2; ++c2) {
            const int k8 = c2 * 4 + quad;
            short8 av[2], bv[4];
#pragma unroll
            for (int i = 0; i < 2; ++i) {
                int arow = wr * 32 + i * 16 + m16;
                av[i] = *(const short8*)&As[arow * 64 + (k8 ^ (arow & 7)) * 8];
            }
#pragma unroll
            for (int j = 0; j < 4; ++j) {
                int brow = wc * 64 + j * 16 + m16;
                bv[j] = *(const short8*)&Bs[brow * 64 + (k8 ^ (brow & 7)) * 8];
            }
#pragma unroll
            for (int i = 0; i < 2; ++i)
#pragma unroll
                for (int j = 0; j < 4; ++j)
                    acc[i][j] = __builtin_amdgcn_mfma_f32_16x16x32_bf16(av[i], bv[j], acc[i][j], 0, 0, 0);
            if (wc == 0) {
                short8 wv = *(const short8*)&W16s[m16 * 648 + k0 + c2 * 32 + quad * 8];
                acc16[0] = __builtin_amdgcn_mfma_f32_16x16x32_bf16(av[0], wv, acc16[0], 0, 0, 0);
                acc16[1] = __builtin_amdgcn_mfma_f32_16x16x32_bf16(av[1], wv, acc16[1], 0, 0, 0);
            }
        }
        __syncthreads();
    }

    // logits -> LDS (wc==0 waves cover all 64 rows x 16 logits)
    if (wc == 0) {
#pragma unroll
        for (int i = 0; i < 2; ++i)
#pragma unroll
            for (int r = 0; r < 4; ++r)
                logitS[(wr * 32 + i * 16 + quad * 4 + r) * 17 + m16] = acc16[i][r];
    }
    __syncthreads();

    // per-row softmax-cumsum (fm l2r, im r2l), dist
    if (tid < 64) {
        int m = m0 + tid;
        float dt = tme[(size_t)m * T + t];
        float z[16];
#pragma unroll
        for (int n = 0; n < 16; ++n) z[n] = logitS[tid * 17 + n] + bias16[n] + dt * wrow16[n];
        float mx = z[0];
#pragma unroll
        for (int j = 1; j < L; ++j) mx = fmaxf(mx, z[j]);
        float e[L], s = 0.f;
#pragma unroll
        for (int j = 0; j < L; ++j) { e[j] = expf(z[j] - mx); s += e[j]; }
        float run = 0.f, fsum = 0.f;
#pragma unroll
        for (int j = 0; j < L; ++j) { run += e[j]; float fmv = run / s; fmimS[tid * 16 + j] = fmv; fsum += fmv; }
        mx = z[L];
#pragma unroll
        for (int j = 1; j < L; ++j) mx = fmaxf(mx, z[L + j]);
        s = 0.f;
#pragma unroll
        for (int j = 0; j < L; ++j) { e[j] = expf(z[L + j] - mx); s += e[j]; }
        run = 0.f;
#pragma unroll
        for (int j = L - 1; j >= 0; --j) { run += e[j]; fmimS[tid * 16 + 8 + j] = run / s; }
        if (nt == 0) {
            float d = 1.0f - fsum / (float)L;
            dist_out[(size_t)t * B + m] = d;
            if (t >= T - KW) tmp_dis[(size_t)(t - (T - KW)) * B + m] = d;
        }
    }
    __syncthreads();

    // gates + cell update
    const int hcol = nt * 32 + wc * 16 + m16;
    const int lidx = hcol >> 6;
    float bj[4], wj[4];
#pragma unroll
    for (int j = 0; j < 4; ++j) {
        int col = nt * 128 + wc * 64 + j * 16 + m16;
        bj[j] = biasg[col];
        wj[j] = wrowg[col];
    }
#pragma unroll
    for (int i = 0; i < 2; ++i) {
#pragma unroll
        for (int r = 0; r < 4; ++r) {
            int rl = wr * 32 + i * 16 + quad * 4 + r;
            int m = m0 + rl;
            float dt = tme[(size_t)m * T + t];
            float fmv = fmimS[rl * 16 + lidx];
            float imv = fmimS[rl * 16 + 8 + lidx];
            float fg = sigmoidf_(acc[i][0][r] + bj[0] + dt * wj[0]);
            float ig = sigmoidf_(acc[i][1][r] + bj[1] + dt * wj[1]);
            float og = sigmoidf_(acc[i][2][r] + bj[2] + dt * wj[2]);
            float ci = tanhf(acc[i][3][r] + bj[3] + dt * wj[3]);
            float ov = fmv * imv;
            size_t off = (size_t)m * H + hcol;
            float cl = c[off];
            float cn = ov * (fg * cl + ig * ci) + (fmv - ov) * cl + (imv - ov) * ci;
            float hn = og * tanhf(cn);
            c[off] = cn;
            __hip_bfloat16 hb = __float2bfloat16(hn);
            hout[off] = hb;
            if (t >= T - KW) tmp_h[((size_t)(t - (T - KW)) * B + m) * H + hcol] = hb;
        }
    }
}

// ---------- post ----------
__global__ __launch_bounds__(128) void post_local(
    const __hip_bfloat16* __restrict__ tmp_h, const float* __restrict__ tmp_dis,
    float* __restrict__ mean_h, __hip_bfloat16* __restrict__ Ahk)
{
    const int b = blockIdx.x;
    const int tid = threadIdx.x;
    __shared__ float ld[KW];
    if (tid == 0) {
        float cd[KW];
        float run = 0.f;
        for (int k = 0; k < KW; ++k) { run += tmp_dis[(size_t)k * B + b]; cd[k] = run; }
        float mx = cd[0];
        for (int k = 1; k < KW; ++k) mx = fmaxf(mx, cd[k]);
        float s = 0.f;
        for (int k = 0; k < KW; ++k) { cd[k] = expf(cd[k] - mx); s += cd[k]; }
        for (int k = 0; k < KW; ++k) ld[k] = cd[k] / s;
    }
    __syncthreads();
    float ldr[KW];
#pragma unroll
    for (int k = 0; k < KW; ++k) ldr[k] = ld[k];
    for (int h = tid; h < H; h += 128) {
        float s = 0.f;
#pragma unroll
        for (int k = 0; k < KW; ++k) {
            float v = __bfloat162float(tmp_h[((size_t)k * B + b) * H + h]) * ldr[k];
            s += v;
            Ahk[(size_t)b * RC + h * KW + k] = __float2bfloat16(v);
        }
        mean_h[(size_t)b * H + h] = s * (1.0f / KW);
    }
}

__global__ void theme1_k(const float* __restrict__ mean_h, const float* __restrict__ Ws,
                         const float* __restrict__ bs, float* __restrict__ t1)
{
    int idx = blockIdx.x * blockDim.x + threadIdx.x;
    if (idx >= B * HS) return;
    int b = idx / HS, j = idx % HS;
    float s = bs[j];
    const float* mh = mean_h + (size_t)b * H;
    for (int h = 0; h < H; ++h) s += mh[h] * Ws[(size_t)h * HS + j];
    t1[idx] = fmaxf(s, 0.f);
}

__global__ void theme2_k(const float* __restrict__ t1, const float* __restrict__ Wrs,
                         const float* __restrict__ brs, float* __restrict__ theme)
{
    int idx = blockIdx.x * blockDim.x + threadIdx.x;
    if (idx >= B * H) return;
    int b = idx / H, o = idx % H;
    float s = brs[o];
    const float* tv = t1 + (size_t)b * HS;
    for (int j = 0; j < HS; ++j) s += tv[j] * Wrs[(size_t)j * H + o];
    theme[idx] = sigmoidf_(s);
}

// conv einsum, split-K: grid (4 n, 16 m, 8 ks); each block K=640, partial to Pbuf.
__global__ __launch_bounds__(256) void conv_split(
    const __hip_bfloat16* __restrict__ Ahk, const __hip_bfloat16* __restrict__ CWb,
    float* __restrict__ Pbuf)
{
    __shared__ __align__(16) unsigned short As2[128 * 64];
    __shared__ __align__(16) unsigned short Bs2[128 * 64];
    const int tid = threadIdx.x;
    const int wave = tid >> 6, lane = tid & 63;
    const int wr = wave >> 1, wc = wave & 1;
    const int quad = lane >> 4, m16 = lane & 15;
    const int n0 = blockIdx.x * 128, m0 = blockIdx.y * 128;
    const int ksb = blockIdx.z * (RC / KS);

    f32x4 acc[4][4] = {};
    for (int k0 = 0; k0 < RC / KS; k0 += 64) {
#pragma unroll
        for (int p = 0; p < 4; ++p) {
            int o = p * 4096 + tid * 16;
            int row = o >> 7, slot = (o >> 4) & 7;
            int kg = ksb + k0 + (slot ^ (row & 7)) * 8;
            gl_lds16((const unsigned short*)Ahk + (size_t)(m0 + row) * RC + kg, (char*)As2 + o);
            gl_lds16((const unsigned short*)CWb + (size_t)(n0 + row) * RC + kg, (char*)Bs2 + o);
        }
        __syncthreads();
#pragma unroll
        for (int c2 = 0; c2 < 2; ++c2) {
            const int k8 = c2 * 4 + quad;
            short8 av[4], bv[4];
#pragma unroll
            for (int i = 0; i < 4; ++i) {
                int arow = wr * 64 + i * 16 + m16;
                av[i] = *(const short8*)&As2[arow * 64 + (k8 ^ (arow & 7)) * 8];
            }
#pragma unroll
            for (int j = 0; j < 4; ++j) {
                int brow = wc * 64 + j * 16 + m16;
                bv[j] = *(const short8*)&Bs2[brow * 64 + (k8 ^ (brow & 7)) * 8];
            }
#pragma unroll
            for (int i = 0; i < 4; ++i)
#pragma unroll
                for (int j = 0; j < 4; ++j)
                    acc[i][j] = __builtin_amdgcn_mfma_f32_16x16x32_bf16(av[i], bv[j], acc[i][j], 0, 0, 0);
        }
        __syncthreads();
    }
    float* P = Pbuf + (size_t)blockIdx.z * B * H;
#pragma unroll
    for (int j = 0; j < 4; ++j) {
        const int col = n0 + wc * 64 + j * 16 + m16;
#pragma unroll
        for (int i = 0; i < 4; ++i) {
            const int rb = m0 + wr * 64 + i * 16 + quad * 4;
#pragma unroll
            for (int r = 0; r < 4; ++r)
                P[(size_t)(rb + r) * H + col] = acc[i][j][r];
        }
    }
}

__global__ void conv_reduce(const float* __restrict__ Pbuf, const float* __restrict__ conv_b,
                            const float* __restrict__ theme, float* __restrict__ out0)
{
    int i = blockIdx.x * blockDim.x + threadIdx.x;
    if (i >= B * H) return;
    float s = conv_b[i & (H - 1)];
#pragma unroll
    for (int ks = 0; ks < KS; ++ks) s += Pbuf[(size_t)ks * B * H + i];
    out0[i] = theme[i] * s;
}

} // namespace

extern "C" void kernel_launch(void* const* d_in, const int* in_sizes, int n_in,
                              void* d_out, int out_size, void* d_ws, size_t ws_size,
                              hipStream_t stream)
{
    (void)in_sizes; (void)n_in; (void)out_size; (void)ws_size;
    const float* x      = (const float*)d_in[0];
    const float* tme    = (const float*)d_in[1];
    const float* Wk     = (const float*)d_in[2];
    const float* bk     = (const float*)d_in[3];
    const float* Wr     = (const float*)d_in[4];
    const float* br     = (const float*)d_in[5];
    const float* Ws     = (const float*)d_in[6];
    const float* bs     = (const float*)d_in[7];
    const float* Wrs    = (const float*)d_in[8];
    const float* brs    = (const float*)d_in[9];
    const float* conv_w = (const float*)d_in[10];
    const float* conv_b = (const float*)d_in[11];

    float* out0 = (float*)d_out;
    float* dist_out = out0 + (size_t)B * H;

    // workspace carve (~168 MB)
    char* w = (char*)d_ws;
    __hip_bfloat16* WgT  = (__hip_bfloat16*)w; w += (size_t)NG * KIN * 2;
    __hip_bfloat16* W16T = (__hip_bfloat16*)w; w += (size_t)16 * KIN * 2;
    __hip_bfloat16* xb   = (__hip_bfloat16*)w; w += (size_t)B * T * F * 2;
    __hip_bfloat16* CWb  = (__hip_bfloat16*)w; w += (size_t)H * RC * 2;
    __hip_bfloat16* Ahk  = (__hip_bfloat16*)w; w += (size_t)B * RC * 2;
    __hip_bfloat16* hb0  = (__hip_bfloat16*)w; w += (size_t)B * H * 2;
    __hip_bfloat16* hb1  = (__hip_bfloat16*)w; w += (size_t)B * H * 2;
    __hip_bfloat16* tmp_h = (__hip_bfloat16*)w; w += (size_t)KW * B * H * 2;
    float* biasg  = (float*)w; w += (size_t)NG * 4;
    float* wrowg  = (float*)w; w += (size_t)NG * 4;
    float* bias16 = (float*)w; w += 64;
    float* wrow16 = (float*)w; w += 64;
    float* c      = (float*)w; w += (size_t)B * H * 4;
    float* tmp_ds = (float*)w; w += (size_t)KW * B * 4;
    float* mean_h = (float*)w; w += (size_t)B * H * 4;
    float* t1     = (float*)w; w += (size_t)B * HS * 4;
    float* theme  = (float*)w; w += (size_t)B * H * 4;
    float* Pbuf   = (float*)w; w += (size_t)KS * B * H * 4;

    hipMemsetAsync(c, 0, (size_t)B * H * sizeof(float), stream);
    hipMemsetAsync(hb0, 0, (size_t)B * H * sizeof(__hip_bfloat16), stream);

    prep_wgt<<<dim3(NG / 64, KIN / 64), 256, 0, stream>>>(Wk, Wr, WgT);
    prep_small<<<1, 256, 0, stream>>>(Wk, bk, Wr, br, W16T, biasg, wrowg, bias16, wrow16);
    convert_x<<<((B * T * F / 4) + 255) / 256, 256, 0, stream>>>(x, xb);
    prep_convw<<<((H * RC / 4) + 255) / 256, 256, 0, stream>>>(conv_w, CWb);

    for (int t = 0; t < T; ++t) {
        const __hip_bfloat16* hin = (t & 1) ? hb1 : hb0;
        __hip_bfloat16* hout = (t & 1) ? hb0 : hb1;
        step_fused<<<dim3(NG / 128, B / 64), 256, 0, stream>>>(
            xb, hin, hout, WgT, W16T, biasg, wrowg, bias16, wrow16,
            tme, c, tmp_h, tmp_ds, dist_out, t);
    }

    post_local<<<B, 128, 0, stream>>>(tmp_h, tmp_ds, mean_h, Ahk);
    theme1_k<<<(B * HS + 255) / 256, 256, 0, stream>>>(mean_h, Ws, bs, t1);
    theme2_k<<<(B * H + 255) / 256, 256, 0, stream>>>(t1, Wrs, brs, theme);
    conv_split<<<dim3(H / 128, B / 128, KS), 256, 0, stream>>>(Ahk, CWb, Pbuf);
    conv_reduce<<<(B * H + 255) / 256, 256, 0, stream>>>(Pbuf, conv_b, theme, out0);
}